// Round 3
// baseline (479.031 us; speedup 1.0000x reference)
//
#include <hip/hip_runtime.h>
#include <hip/hip_bf16.h>

typedef __bf16 bf16;
typedef __bf16 bf16x4 __attribute__((ext_vector_type(4)));
typedef __bf16 bf16x8 __attribute__((ext_vector_type(8)));
typedef float f32x4 __attribute__((ext_vector_type(4)));

// workspace layout (bytes)
#define WS_INV 262144           // 512 f32
#define WS_ADD 264192           // 512 f32
#define WS_BIAS 266240          // 16*64*64 f32 = 256KB
#define WS_QKT 1048576          // 1152 * 66560 B = 76,677,120 B

#define XS_STRIDE 264           // bf16 elems per xs row (528B)
#define QK_STRIDE 520           // bf16 elems per qk row (1040B)
#define QK_WIN_BYTES 66560      // 64 * 520 * 2

#define LDS_AVG_OFF 66560
#define LDS_STG_OFF 68608
#define STG_STRIDE 68
#define LDS_B_BYTES (68608 + 8704)

// ---------------- prep: w->bf16, BN fold, bias table ----------------
__global__ void prep_kernel(const float* __restrict__ w_qk,
                            const float* __restrict__ gamma,
                            const float* __restrict__ beta,
                            const float* __restrict__ rmean,
                            const float* __restrict__ rvar,
                            const float* __restrict__ rel_table,
                            char* __restrict__ ws) {
  bf16* wbf = (bf16*)ws;
  float* invb = (float*)(ws + WS_INV);
  float* addb = (float*)(ws + WS_ADD);
  float* biasb = (float*)(ws + WS_BIAS);
  int bid = blockIdx.x, t = threadIdx.x;
  if (bid < 512) {
    int o = bid;
    wbf[o * 256 + t] = (bf16)w_qk[o * 256 + t];
    if (t == 0) {
      float iv = gamma[o] * rsqrtf(rvar[o] + 1e-5f);
      invb[o] = iv;
      addb[o] = beta[o] - rmean[o] * iv;
    }
  } else {
    int base = (bid - 512) * 1024 + t * 4;
#pragma unroll
    for (int i = 0; i < 4; ++i) {
      int flat = base + i;
      int h = flat >> 12, n = (flat >> 6) & 63, m = flat & 63;
      int idx = ((n >> 3) - (m >> 3) + 7) * 15 + ((n & 7) - (m & 7) + 7);
      biasb[flat] = rel_table[idx * 16 + h];
    }
  }
}

// ---------------- kernel A: conv1x1+BN+ReLU per window -> qkt[win][px][520] bf16 ----------------
__global__ __launch_bounds__(512)
void gemm_kernel(const float* __restrict__ x, char* __restrict__ ws) {
  const bf16* __restrict__ wbf = (const bf16*)ws;
  const float* __restrict__ invb = (const float*)(ws + WS_INV);
  const float* __restrict__ addb = (const float*)(ws + WS_ADD);
  bf16* __restrict__ qkt = (bf16*)(ws + WS_QKT);

  __shared__ __attribute__((aligned(16))) char smem[QK_WIN_BYTES];
  bf16* xs = (bf16*)smem;          // [64][264] during phases 1-2
  bf16* qk = (bf16*)smem;          // [64][520] epilogue (overlaps xs)

  const int bid = blockIdx.x;
  const int win = (bid & 7) * 144 + (bid >> 3);   // XCD-bijective swizzle
  const int b = win / 576;
  const int rem = win - b * 576;
  const int wy = rem / 24, wx = rem - (rem / 24) * 24;

  const int tid = threadIdx.x;
  const int w = tid >> 6;
  const int l = tid & 63;
  const int lg = l >> 4;
  const int ll = l & 15;

  // ---- phase 1: stage x window -> xs[px][c] bf16 ----
  {
    const float* xb = x + (size_t)b * 256 * 36864 + (size_t)(wy * 8) * 192 + wx * 8;
    const int c = tid & 255;
    const int half = tid >> 8;
#pragma unroll
    for (int p = 0; p < 4; ++p) {
      int ws1 = p * 2 + half;
      const float* src = xb + (size_t)c * 36864 + ws1 * 192;
      float4 v0 = *(const float4*)src;
      float4 v1 = *(const float4*)(src + 4);
      bf16* dst = xs + (ws1 * 8) * XS_STRIDE + c;
      dst[0 * XS_STRIDE] = (bf16)v0.x;
      dst[1 * XS_STRIDE] = (bf16)v0.y;
      dst[2 * XS_STRIDE] = (bf16)v0.z;
      dst[3 * XS_STRIDE] = (bf16)v0.w;
      dst[4 * XS_STRIDE] = (bf16)v1.x;
      dst[5 * XS_STRIDE] = (bf16)v1.y;
      dst[6 * XS_STRIDE] = (bf16)v1.z;
      dst[7 * XS_STRIDE] = (bf16)v1.w;
    }
  }
  __syncthreads();

  // ---- phase 2: GEMM.  wave w owns out-channels [w*64, w*64+64) x 64 px ----
  f32x4 acc[4][4];
#pragma unroll
  for (int mt = 0; mt < 4; ++mt)
#pragma unroll
    for (int nt = 0; nt < 4; ++nt)
      acc[mt][nt] = (f32x4){0.f, 0.f, 0.f, 0.f};

  const int obase = w * 64;
  for (int kk = 0; kk < 8; ++kk) {
    bf16x8 a[4], bb[4];
#pragma unroll
    for (int mt = 0; mt < 4; ++mt)
      a[mt] = *(const bf16x8*)(wbf + (size_t)(obase + mt * 16 + ll) * 256 + kk * 32 + lg * 8);
#pragma unroll
    for (int nt = 0; nt < 4; ++nt)
      bb[nt] = *(const bf16x8*)(xs + (nt * 16 + ll) * XS_STRIDE + kk * 32 + lg * 8);
#pragma unroll
    for (int mt = 0; mt < 4; ++mt)
#pragma unroll
      for (int nt = 0; nt < 4; ++nt)
        acc[mt][nt] = __builtin_amdgcn_mfma_f32_16x16x32_bf16(a[mt], bb[nt], acc[mt][nt], 0, 0, 0);
  }
  __syncthreads();   // all waves done reading xs; qk overlaps it

  // epilogue: BN + ReLU -> qk[px][o] bf16 (vector ds_write_b64)
#pragma unroll
  for (int mt = 0; mt < 4; ++mt) {
    const int ob = obase + mt * 16 + lg * 4;
    float iv0 = invb[ob + 0], iv1 = invb[ob + 1], iv2 = invb[ob + 2], iv3 = invb[ob + 3];
    float ad0 = addb[ob + 0], ad1 = addb[ob + 1], ad2 = addb[ob + 2], ad3 = addb[ob + 3];
#pragma unroll
    for (int nt = 0; nt < 4; ++nt) {
      int px = nt * 16 + ll;
      bf16x4 pack;
      pack[0] = (bf16)fmaxf(acc[mt][nt][0] * iv0 + ad0, 0.f);
      pack[1] = (bf16)fmaxf(acc[mt][nt][1] * iv1 + ad1, 0.f);
      pack[2] = (bf16)fmaxf(acc[mt][nt][2] * iv2 + ad2, 0.f);
      pack[3] = (bf16)fmaxf(acc[mt][nt][3] * iv3 + ad3, 0.f);
      *(bf16x4*)(qk + px * QK_STRIDE + ob) = pack;
    }
  }
  __syncthreads();

  // store LDS image -> qkt[win] (coalesced, 16B/lane)
  {
    char* dst = (char*)(qkt) + (size_t)win * QK_WIN_BYTES;
#pragma unroll
    for (int it = 0; it < 8; ++it) {
      int byte = (it * 512 + tid) * 16;
      *(f32x4*)(dst + byte) = *(const f32x4*)(smem + byte);
    }
    if (tid < 64) {
      int byte = 65536 + tid * 16;
      *(f32x4*)(dst + byte) = *(const f32x4*)(smem + byte);
    }
  }
}

// ---------------- kernel B: QK^T+bias -> softmax+avg, per window ----------------
__global__ __launch_bounds__(512, 4)
void attn_kernel(const char* __restrict__ ws,
                 float* __restrict__ out_attn, float* __restrict__ out_avg) {
  const float* __restrict__ biasb = (const float*)(ws + WS_BIAS);
  const bf16* __restrict__ qkt = (const bf16*)(ws + WS_QKT);

  __shared__ __attribute__((aligned(16))) char smem[LDS_B_BYTES];
  bf16* qk = (bf16*)smem;                       // [64][520]
  float* avgp = (float*)(smem + LDS_AVG_OFF);   // [8][64]

  const int bid = blockIdx.x;
  const int win = (bid & 7) * 144 + (bid >> 3);

  const int tid = threadIdx.x;
  const int w = tid >> 6;
  const int l = tid & 63;
  const int lg = l >> 4;
  const int ll = l & 15;

  float* stgw = (float*)(smem + LDS_STG_OFF) + w * (4 * STG_STRIDE);

  // load qkt[win] -> LDS (coalesced, identical linear image)
  {
    const char* src = (const char*)(qkt) + (size_t)win * QK_WIN_BYTES;
#pragma unroll
    for (int it = 0; it < 8; ++it) {
      int byte = (it * 512 + tid) * 16;
      *(f32x4*)(smem + byte) = *(const f32x4*)(src + byte);
    }
    if (tid < 64) {
      int byte = 65536 + tid * 16;
      *(f32x4*)(smem + byte) = *(const f32x4*)(src + byte);
    }
  }
  __syncthreads();

  bf16x8 zfrag;
#pragma unroll
  for (int i = 0; i < 8; ++i) zfrag[i] = (bf16)0.f;

  float psum[4] = {0.f, 0.f, 0.f, 0.f};

  for (int hh = 0; hh < 2; ++hh) {
    const int h = w * 2 + hh;
    bf16x8 qa[4];
#pragma unroll
    for (int nt = 0; nt < 4; ++nt) {
      bf16x8 v = *(const bf16x8*)(qk + (nt * 16 + ll) * QK_STRIDE + h * 16 + (lg & 1) * 8);
      qa[nt] = (l < 32) ? v : zfrag;
    }
    f32x4 s[4][4];
#pragma unroll
    for (int mt = 0; mt < 4; ++mt) {
      bf16x8 kb = *(const bf16x8*)(qk + (mt * 16 + ll) * QK_STRIDE + 256 + h * 16 + (lg & 1) * 8);
      kb = (l < 32) ? kb : zfrag;
#pragma unroll
      for (int nt = 0; nt < 4; ++nt) {
        f32x4 z = {0.f, 0.f, 0.f, 0.f};
        s[nt][mt] = __builtin_amdgcn_mfma_f32_16x16x32_bf16(qa[nt], kb, z, 0, 0, 0);
      }
    }
    const float* bh = biasb + h * 4096;
#pragma unroll
    for (int nt = 0; nt < 4; ++nt) {
#pragma unroll
      for (int j = 0; j < 4; ++j) {
        int n = nt * 16 + lg * 4 + j;
#pragma unroll
        for (int mt = 0; mt < 4; ++mt) {
          float v = s[nt][mt][j] * 0.25f + bh[n * 64 + mt * 16 + ll];
          s[nt][mt][j] = v;
          psum[mt] += v;
        }
      }
    }
#pragma unroll
    for (int nt = 0; nt < 4; ++nt) {
#pragma unroll
      for (int j = 0; j < 4; ++j) {
        float mx = fmaxf(fmaxf(s[nt][0][j], s[nt][1][j]), fmaxf(s[nt][2][j], s[nt][3][j]));
        mx = fmaxf(mx, __shfl_xor(mx, 1));
        mx = fmaxf(mx, __shfl_xor(mx, 2));
        mx = fmaxf(mx, __shfl_xor(mx, 4));
        mx = fmaxf(mx, __shfl_xor(mx, 8));
        float sum = 0.f;
#pragma unroll
        for (int mt = 0; mt < 4; ++mt) {
          float e = __expf(s[nt][mt][j] - mx);
          s[nt][mt][j] = e;
          sum += e;
        }
        sum += __shfl_xor(sum, 1);
        sum += __shfl_xor(sum, 2);
        sum += __shfl_xor(sum, 4);
        sum += __shfl_xor(sum, 8);
        float rinv = __builtin_amdgcn_rcpf(sum);
#pragma unroll
        for (int mt = 0; mt < 4; ++mt)
          stgw[lg * STG_STRIDE + mt * 16 + ll] = s[nt][mt][j] * rinv;
        f32x4 v = *(const f32x4*)(stgw + lg * STG_STRIDE + 4 * ll);
        int n = nt * 16 + lg * 4 + j;
        *(f32x4*)(out_attn + ((size_t)(win * 16 + h) * 64 + n) * 64 + 4 * ll) = v;
      }
    }
  }

#pragma unroll
  for (int mt = 0; mt < 4; ++mt) {
    psum[mt] += __shfl_xor(psum[mt], 16);
    psum[mt] += __shfl_xor(psum[mt], 32);
  }
  if (l < 16) {
#pragma unroll
    for (int mt = 0; mt < 4; ++mt)
      avgp[w * 64 + mt * 16 + l] = psum[mt];
  }
  __syncthreads();
  if (tid < 64) {
    float t = 0.f;
#pragma unroll
    for (int w2 = 0; w2 < 8; ++w2) t += avgp[w2 * 64 + tid];
    out_avg[win * 64 + tid] = t * (1.f / 1024.f);
  }
}

extern "C" void kernel_launch(void* const* d_in, const int* in_sizes, int n_in,
                              void* d_out, int out_size, void* d_ws, size_t ws_size,
                              hipStream_t stream) {
  const float* x     = (const float*)d_in[0];
  const float* w_qk  = (const float*)d_in[1];
  const float* gamma = (const float*)d_in[2];
  const float* beta  = (const float*)d_in[3];
  const float* rmean = (const float*)d_in[4];
  const float* rvar  = (const float*)d_in[5];
  const float* rel   = (const float*)d_in[6];
  float* out = (float*)d_out;
  char* ws = (char*)d_ws;

  prep_kernel<<<576, 256, 0, stream>>>(w_qk, gamma, beta, rmean, rvar, rel, ws);
  gemm_kernel<<<1152, 512, 0, stream>>>(x, ws);
  attn_kernel<<<1152, 512, 0, stream>>>(ws, out, out + (size_t)75497472);
}

// Round 4
// 478.932 us; speedup vs baseline: 1.0002x; 1.0002x over previous
//
#include <hip/hip_runtime.h>
#include <hip/hip_bf16.h>

typedef __bf16 bf16;
typedef __bf16 bf16x4 __attribute__((ext_vector_type(4)));
typedef __bf16 bf16x8 __attribute__((ext_vector_type(8)));
typedef float f32x4 __attribute__((ext_vector_type(4)));

// workspace layout (bytes)
#define WS_INV 262144           // 512 f32
#define WS_ADD 264192           // 512 f32
#define WS_BIAS 266240          // 16*64*64 f32 = 256KB
#define WS_QKT 1048576          // dense qkt: 1152 * 65536 B = 75,497,472 B

#define XS_STRIDE 264           // bf16 elems per xs row (528B)
#define QK_STRIDE 520           // bf16 elems per qk row in LDS (1040B)
#define QK_WIN_BYTES 65536      // dense: 64 px * 512 oc * 2B

#define LDS_AVG_OFF 66560       // 64*1040
#define LDS_STG_OFF 68608
#define STG_STRIDE 68
#define LDS_B_BYTES (68608 + 8704)

// ---------------- prep: w->bf16, BN fold, bias table ----------------
__global__ void prep_kernel(const float* __restrict__ w_qk,
                            const float* __restrict__ gamma,
                            const float* __restrict__ beta,
                            const float* __restrict__ rmean,
                            const float* __restrict__ rvar,
                            const float* __restrict__ rel_table,
                            char* __restrict__ ws) {
  bf16* wbf = (bf16*)ws;
  float* invb = (float*)(ws + WS_INV);
  float* addb = (float*)(ws + WS_ADD);
  float* biasb = (float*)(ws + WS_BIAS);
  int bid = blockIdx.x, t = threadIdx.x;
  if (bid < 512) {
    int o = bid;
    wbf[o * 256 + t] = (bf16)w_qk[o * 256 + t];
    if (t == 0) {
      float iv = gamma[o] * rsqrtf(rvar[o] + 1e-5f);
      invb[o] = iv;
      addb[o] = beta[o] - rmean[o] * iv;
    }
  } else {
    int base = (bid - 512) * 1024 + t * 4;
#pragma unroll
    for (int i = 0; i < 4; ++i) {
      int flat = base + i;
      int h = flat >> 12, n = (flat >> 6) & 63, m = flat & 63;
      int idx = ((n >> 3) - (m >> 3) + 7) * 15 + ((n & 7) - (m & 7) + 7);
      biasb[flat] = rel_table[idx * 16 + h];
    }
  }
}

// ---------------- kernel A: row-band GEMM, coalesced x reads ----------------
// block = (b, h, third): 64 contiguous px of one image row, all 512 out-ch.
__global__ __launch_bounds__(512)
void gemm_kernel(const float* __restrict__ x, char* __restrict__ ws) {
  const bf16* __restrict__ wbf = (const bf16*)ws;
  const float* __restrict__ invb = (const float*)(ws + WS_INV);
  const float* __restrict__ addb = (const float*)(ws + WS_ADD);
  bf16* __restrict__ qkt = (bf16*)(ws + WS_QKT);

  __shared__ __attribute__((aligned(16))) char smem[64 * XS_STRIDE * 2];  // 33792 B
  bf16* xs = (bf16*)smem;   // [64 px][264]

  const int tile = blockIdx.x;           // 0..1151
  const int b = tile / 576;
  const int r = tile - b * 576;
  const int h = r / 3;
  const int third = r - h * 3;

  const int tid = threadIdx.x;
  const int w = tid >> 6;
  const int l = tid & 63;
  const int lg = l >> 4;
  const int ll = l & 15;

  // ---- stage: fully coalesced (4 c-rows x 256B per wave-instr) ----
  {
    const float* xrow = x + (size_t)b * 256 * 36864 + h * 192 + third * 64;
    const int cbase = tid >> 4;          // 0..31
    const int px4 = (tid & 15) * 4;
#pragma unroll
    for (int p = 0; p < 8; ++p) {
      int c = p * 32 + cbase;
      float4 v = *(const float4*)(xrow + (size_t)c * 36864 + px4);
      xs[(px4 + 0) * XS_STRIDE + c] = (bf16)v.x;
      xs[(px4 + 1) * XS_STRIDE + c] = (bf16)v.y;
      xs[(px4 + 2) * XS_STRIDE + c] = (bf16)v.z;
      xs[(px4 + 3) * XS_STRIDE + c] = (bf16)v.w;
    }
  }
  __syncthreads();

  // ---- GEMM: wave w owns out-channels [w*64, w*64+64) x 64 px ----
  f32x4 acc[4][4];
#pragma unroll
  for (int mt = 0; mt < 4; ++mt)
#pragma unroll
    for (int nt = 0; nt < 4; ++nt)
      acc[mt][nt] = (f32x4){0.f, 0.f, 0.f, 0.f};

  const int obase = w * 64;
  for (int kk = 0; kk < 8; ++kk) {
    bf16x8 a[4], bb[4];
#pragma unroll
    for (int mt = 0; mt < 4; ++mt)
      a[mt] = *(const bf16x8*)(wbf + (size_t)(obase + mt * 16 + ll) * 256 + kk * 32 + lg * 8);
#pragma unroll
    for (int nt = 0; nt < 4; ++nt)
      bb[nt] = *(const bf16x8*)(xs + (nt * 16 + ll) * XS_STRIDE + kk * 32 + lg * 8);
#pragma unroll
    for (int mt = 0; mt < 4; ++mt)
#pragma unroll
      for (int nt = 0; nt < 4; ++nt)
        acc[mt][nt] = __builtin_amdgcn_mfma_f32_16x16x32_bf16(a[mt], bb[nt], acc[mt][nt], 0, 0, 0);
  }

  // ---- epilogue: BN+ReLU -> dense qkt[win][pxw][oc] bf16, direct global store ----
  const int winBase = b * 576 + (h >> 3) * 24 + third * 8;
  const int pxwRow = (h & 7) * 8;
#pragma unroll
  for (int mt = 0; mt < 4; ++mt) {
    const int ob = obase + mt * 16 + lg * 4;
    float iv0 = invb[ob + 0], iv1 = invb[ob + 1], iv2 = invb[ob + 2], iv3 = invb[ob + 3];
    float ad0 = addb[ob + 0], ad1 = addb[ob + 1], ad2 = addb[ob + 2], ad3 = addb[ob + 3];
#pragma unroll
    for (int nt = 0; nt < 4; ++nt) {
      int px = nt * 16 + ll;
      int win = winBase + (px >> 3);
      int pxw = pxwRow + (px & 7);
      bf16x4 pack;
      pack[0] = (bf16)fmaxf(acc[mt][nt][0] * iv0 + ad0, 0.f);
      pack[1] = (bf16)fmaxf(acc[mt][nt][1] * iv1 + ad1, 0.f);
      pack[2] = (bf16)fmaxf(acc[mt][nt][2] * iv2 + ad2, 0.f);
      pack[3] = (bf16)fmaxf(acc[mt][nt][3] * iv3 + ad3, 0.f);
      *(bf16x4*)(qkt + (size_t)win * 32768 + pxw * 512 + ob) = pack;
    }
  }
}

// ---------------- kernel B: QK^T+bias -> softmax+avg, per window ----------------
__global__ __launch_bounds__(512)
void attn_kernel(const char* __restrict__ ws,
                 float* __restrict__ out_attn, float* __restrict__ out_avg) {
  const float* __restrict__ biasb = (const float*)(ws + WS_BIAS);
  const char* __restrict__ qkt = ws + WS_QKT;

  __shared__ __attribute__((aligned(16))) char smem[LDS_B_BYTES];
  bf16* qk = (bf16*)smem;                       // [64][520] (padded rows)
  float* avgp = (float*)(smem + LDS_AVG_OFF);   // [8][64]

  const int bid = blockIdx.x;
  const int win = (bid & 7) * 144 + (bid >> 3);  // XCD-bijective swizzle

  const int tid = threadIdx.x;
  const int w = tid >> 6;
  const int l = tid & 63;
  const int lg = l >> 4;
  const int ll = l & 15;

  float* stgw = (float*)(smem + LDS_STG_OFF) + w * (4 * STG_STRIDE);

  // load dense qkt[win] -> padded LDS rows (coalesced 16B/lane)
  {
    const char* src = qkt + (size_t)win * QK_WIN_BYTES;
#pragma unroll
    for (int p = 0; p < 8; ++p) {
      int k = p * 512 + tid;                 // 16B-chunk index
      int px = k >> 6, c16 = k & 63;
      *(f32x4*)(smem + px * 1040 + c16 * 16) = *(const f32x4*)(src + (size_t)k * 16);
    }
  }
  __syncthreads();

  bf16x8 zfrag;
#pragma unroll
  for (int i = 0; i < 8; ++i) zfrag[i] = (bf16)0.f;

  float psum[4] = {0.f, 0.f, 0.f, 0.f};

  for (int hh = 0; hh < 2; ++hh) {
    const int h = w * 2 + hh;
    bf16x8 qa[4];
#pragma unroll
    for (int nt = 0; nt < 4; ++nt) {
      bf16x8 v = *(const bf16x8*)(qk + (nt * 16 + ll) * QK_STRIDE + h * 16 + (lg & 1) * 8);
      qa[nt] = (l < 32) ? v : zfrag;
    }
    f32x4 s[4][4];
#pragma unroll
    for (int mt = 0; mt < 4; ++mt) {
      bf16x8 kb = *(const bf16x8*)(qk + (mt * 16 + ll) * QK_STRIDE + 256 + h * 16 + (lg & 1) * 8);
      kb = (l < 32) ? kb : zfrag;
#pragma unroll
      for (int nt = 0; nt < 4; ++nt) {
        f32x4 z = {0.f, 0.f, 0.f, 0.f};
        s[nt][mt] = __builtin_amdgcn_mfma_f32_16x16x32_bf16(qa[nt], kb, z, 0, 0, 0);
      }
    }
    const float* bh = biasb + h * 4096;
#pragma unroll
    for (int nt = 0; nt < 4; ++nt) {
#pragma unroll
      for (int j = 0; j < 4; ++j) {
        int n = nt * 16 + lg * 4 + j;
#pragma unroll
        for (int mt = 0; mt < 4; ++mt) {
          float v = s[nt][mt][j] * 0.25f + bh[n * 64 + mt * 16 + ll];
          s[nt][mt][j] = v;
          psum[mt] += v;
        }
      }
    }
#pragma unroll
    for (int nt = 0; nt < 4; ++nt) {
#pragma unroll
      for (int j = 0; j < 4; ++j) {
        float mx = fmaxf(fmaxf(s[nt][0][j], s[nt][1][j]), fmaxf(s[nt][2][j], s[nt][3][j]));
        mx = fmaxf(mx, __shfl_xor(mx, 1));
        mx = fmaxf(mx, __shfl_xor(mx, 2));
        mx = fmaxf(mx, __shfl_xor(mx, 4));
        mx = fmaxf(mx, __shfl_xor(mx, 8));
        float sum = 0.f;
#pragma unroll
        for (int mt = 0; mt < 4; ++mt) {
          float e = __expf(s[nt][mt][j] - mx);
          s[nt][mt][j] = e;
          sum += e;
        }
        sum += __shfl_xor(sum, 1);
        sum += __shfl_xor(sum, 2);
        sum += __shfl_xor(sum, 4);
        sum += __shfl_xor(sum, 8);
        float rinv = __builtin_amdgcn_rcpf(sum);
#pragma unroll
        for (int mt = 0; mt < 4; ++mt)
          stgw[lg * STG_STRIDE + mt * 16 + ll] = s[nt][mt][j] * rinv;
        f32x4 v = *(const f32x4*)(stgw + lg * STG_STRIDE + 4 * ll);
        int n = nt * 16 + lg * 4 + j;
        *(f32x4*)(out_attn + ((size_t)(win * 16 + h) * 64 + n) * 64 + 4 * ll) = v;
      }
    }
  }

#pragma unroll
  for (int mt = 0; mt < 4; ++mt) {
    psum[mt] += __shfl_xor(psum[mt], 16);
    psum[mt] += __shfl_xor(psum[mt], 32);
  }
  if (l < 16) {
#pragma unroll
    for (int mt = 0; mt < 4; ++mt)
      avgp[w * 64 + mt * 16 + l] = psum[mt];
  }
  __syncthreads();
  if (tid < 64) {
    float t = 0.f;
#pragma unroll
    for (int w2 = 0; w2 < 8; ++w2) t += avgp[w2 * 64 + tid];
    out_avg[win * 64 + tid] = t * (1.f / 1024.f);
  }
}

extern "C" void kernel_launch(void* const* d_in, const int* in_sizes, int n_in,
                              void* d_out, int out_size, void* d_ws, size_t ws_size,
                              hipStream_t stream) {
  const float* x     = (const float*)d_in[0];
  const float* w_qk  = (const float*)d_in[1];
  const float* gamma = (const float*)d_in[2];
  const float* beta  = (const float*)d_in[3];
  const float* rmean = (const float*)d_in[4];
  const float* rvar  = (const float*)d_in[5];
  const float* rel   = (const float*)d_in[6];
  float* out = (float*)d_out;
  char* ws = (char*)d_ws;

  prep_kernel<<<576, 256, 0, stream>>>(w_qk, gamma, beta, rmean, rvar, rel, ws);
  gemm_kernel<<<1152, 512, 0, stream>>>(x, ws);
  attn_kernel<<<1152, 512, 0, stream>>>(ws, out, out + (size_t)75497472);
}